// Round 1
// baseline (775.508 us; speedup 1.0000x reference)
//
#include <hip/hip_runtime.h>
#include <math.h>

#define WD 128

// ---- ordered-uint encoding for f32 atomic max ----
__device__ __forceinline__ unsigned ord_encode(float f) {
    unsigned u = __float_as_uint(f);
    return (u & 0x80000000u) ? ~u : (u | 0x80000000u);
}
__device__ __forceinline__ float ord_decode(unsigned e) {
    unsigned u = (e & 0x80000000u) ? (e & 0x7fffffffu) : ~e;
    return __uint_as_float(u);
}
#define ORD_NEG_INF 0x007FFFFFu  // ord_encode(-inf)

// y[i][j] = sum_k x[i][k] * We[k*WD + j], k < 128 (first 128 rows of W_edge)
__global__ __launch_bounds__(256) void gemm_y(const float* __restrict__ x,
                                              const float* __restrict__ We,
                                              float* __restrict__ y, int n) {
    __shared__ float xs[8][WD];
    int j = threadIdx.x & 127;
    int half = threadIdx.x >> 7;  // 0..1
    int row0 = blockIdx.x * 8;
    for (int t = threadIdx.x; t < 8 * WD; t += 256) {
        int r = t >> 7, c = t & 127;
        int gr = row0 + r;
        xs[r][c] = (gr < n) ? x[(size_t)gr * WD + c] : 0.f;
    }
    __syncthreads();
    float acc[4] = {0.f, 0.f, 0.f, 0.f};
    #pragma unroll 8
    for (int k = 0; k < WD; ++k) {
        float w = We[k * WD + j];
        acc[0] = fmaf(xs[half + 0][k], w, acc[0]);
        acc[1] = fmaf(xs[half + 2][k], w, acc[1]);
        acc[2] = fmaf(xs[half + 4][k], w, acc[2]);
        acc[3] = fmaf(xs[half + 6][k], w, acc[3]);
    }
    #pragma unroll
    for (int q = 0; q < 4; ++q) {
        int gr = row0 + half + q * 2;
        if (gr < n) y[(size_t)gr * WD + j] = acc[q];
    }
}

__global__ __launch_bounds__(256) void init_maxes(unsigned* __restrict__ mx, int n) {
    int i = blockIdx.x * 256 + threadIdx.x;
    if (i < n) mx[i] = ORD_NEG_INF;
}

// One thread per (directed edge, feature). 2 directed edges per 256-thread block.
__global__ __launch_bounds__(256) void edge_kernel(const int* __restrict__ ei,
                                                   const float* __restrict__ ef,
                                                   const float* __restrict__ x,
                                                   const float* __restrict__ y,
                                                   const float* __restrict__ We,
                                                   const float* __restrict__ be,
                                                   unsigned* __restrict__ mx,
                                                   int E) {
    int idx = blockIdx.x * 256 + threadIdx.x;
    int e = idx >> 7;  // directed edge id in [0, 2E)
    if (e >= 2 * E) return;
    int j = idx & 127;
    int src, dst, erow;
    if (e < E) {
        erow = e;
        src = ei[e];
        dst = ei[E + e];
    } else {
        erow = e - E;
        src = ei[E + erow];
        dst = ei[erow];
    }
    float ef0 = ef[(size_t)erow * 2 + 0];
    float ef1 = ef[(size_t)erow * 2 + 1];
    float yd = y[(size_t)dst * WD + j];
    float ys = y[(size_t)src * WD + j];
    float xd = x[(size_t)dst * WD + j];
    float xsv = x[(size_t)src * WD + j];
    float h = yd - ys + ef0 * We[128 * WD + j] + ef1 * We[129 * WD + j] + be[j];
    h = fmaxf(h, 0.f);
    float ev = (xd - xsv) + h;
    atomicMax(&mx[(size_t)dst * WD + j], ord_encode(ev));
}

__global__ __launch_bounds__(256) void decode_maxes(unsigned* __restrict__ buf, int n) {
    int i = blockIdx.x * 256 + threadIdx.x;
    if (i < n) {
        float f = ord_decode(buf[i]);
        if (!isfinite(f)) f = 0.f;
        ((float*)buf)[i] = f;
    }
}

// out[i][j] = x[i][j] + relu( sum_k x[i][k]*Wm[k][j] + sum_k mx[i][k]*Wm[128+k][j] + b[j] )
__global__ __launch_bounds__(256) void gemm_out(const float* __restrict__ x,
                                                const float* __restrict__ mx,
                                                const float* __restrict__ Wm,
                                                const float* __restrict__ b,
                                                float* __restrict__ out, int n) {
    __shared__ float xs[8][2 * WD];
    int j = threadIdx.x & 127;
    int half = threadIdx.x >> 7;  // 0..1
    int row0 = blockIdx.x * 8;
    for (int t = threadIdx.x; t < 8 * 2 * WD; t += 256) {
        int r = t >> 8, c = t & 255;
        int gr = row0 + r;
        float v = 0.f;
        if (gr < n) v = (c < WD) ? x[(size_t)gr * WD + c] : mx[(size_t)gr * WD + (c - WD)];
        xs[r][c] = v;
    }
    __syncthreads();
    float acc[4] = {0.f, 0.f, 0.f, 0.f};
    #pragma unroll 8
    for (int k = 0; k < 2 * WD; ++k) {
        float w = Wm[k * WD + j];
        acc[0] = fmaf(xs[half + 0][k], w, acc[0]);
        acc[1] = fmaf(xs[half + 2][k], w, acc[1]);
        acc[2] = fmaf(xs[half + 4][k], w, acc[2]);
        acc[3] = fmaf(xs[half + 6][k], w, acc[3]);
    }
    float bj = b[j];
    #pragma unroll
    for (int q = 0; q < 4; ++q) {
        int gr = row0 + half + q * 2;
        if (gr < n) {
            float xv = x[(size_t)gr * WD + j];
            out[(size_t)gr * WD + j] = xv + fmaxf(acc[q] + bj, 0.f);
        }
    }
}

extern "C" void kernel_launch(void* const* d_in, const int* in_sizes, int n_in,
                              void* d_out, int out_size, void* d_ws, size_t ws_size,
                              hipStream_t stream) {
    const float* x_p = (const float*)d_in[0];
    const int*   ei  = (const int*)d_in[1];
    const float* ef  = (const float*)d_in[2];
    const float* We  = (const float*)d_in[3];
    const float* be  = (const float*)d_in[4];
    const float* Wm  = (const float*)d_in[5];
    const float* bm  = (const float*)d_in[6];

    int n = in_sizes[0] / WD;        // 50000
    int E = in_sizes[1] / 2;         // 800000

    float*    y  = (float*)d_ws;
    unsigned* mx = (unsigned*)((char*)d_ws + (size_t)n * WD * sizeof(float));

    int nw = n * WD;

    gemm_y<<<(n + 7) / 8, 256, 0, stream>>>(x_p, We, y, n);
    init_maxes<<<(nw + 255) / 256, 256, 0, stream>>>(mx, nw);
    // 2E directed edges, 128 threads each, 2 edges per block -> E blocks
    edge_kernel<<<E, 256, 0, stream>>>(ei, ef, x_p, y, We, be, mx, E);
    decode_maxes<<<(nw + 255) / 256, 256, 0, stream>>>(mx, nw);
    gemm_out<<<(n + 7) / 8, 256, 0, stream>>>(x_p, (const float*)mx, Wm, bm,
                                              (float*)d_out, n);
}